// Round 7
// baseline (16443.634 us; speedup 1.0000x reference)
//
#include <hip/hip_runtime.h>
#include <hip/hip_fp16.h>

#define T_LEN 4096
#define HID   256
#define G4    1024
#define DIRSZ (1024 * 128)   // packed weight u32 per direction (1024 rows x 128 pairs)

typedef unsigned int u32;
typedef unsigned long long u64;
typedef _Float16 half2_t __attribute__((ext_vector_type(2)));

__device__ __forceinline__ float dot2f(u32 w, u32 h, float acc) {
#if __has_builtin(__builtin_amdgcn_fdot2)
    return __builtin_amdgcn_fdot2(__builtin_bit_cast(half2_t, w),
                                  __builtin_bit_cast(half2_t, h), acc, false);
#else
    __half2 wh = __builtin_bit_cast(__half2, w);
    __half2 hh = __builtin_bit_cast(__half2, h);
    float2 wf = __half22float2(wh), hf = __half22float2(hh);
    return acc + wf.x * hf.x + wf.y * hf.y;
#endif
}

// dot with wave-uniform h held in an SGPR (VOP3P permits one scalar source).
// Bitwise-identical arithmetic to dot2f; only the operand register class differs.
__device__ __forceinline__ float dot2s(u32 w, u32 hs, float acc) {
    asm("v_dot2_f32_f16 %0, %1, %2, %0" : "+v"(acc) : "v"(w), "s"(hs));
    return acc;
}

__device__ __forceinline__ u32 pack2(float a, float b) {
    unsigned short lo = __half_as_ushort(__float2half(a));
    unsigned short hi = __half_as_ushort(__float2half(b));
    return ((u32)hi << 16) | (u32)lo;
}

// lgkm-only barrier: never drains vmcnt (global stores/loads keep flying)
__device__ __forceinline__ void step_barrier() {
    asm volatile("s_waitcnt lgkmcnt(0)" ::: "memory");
    __builtin_amdgcn_s_barrier();
    __builtin_amdgcn_sched_barrier(0);
}

// ---------------- zero helper (exchange tags must be 0 at each launch) -------
__global__ void k_zero(u32* __restrict__ p, int n) {
    int q = blockIdx.x * 256 + threadIdx.x;
    if (q < n) p[q] = 0u;
}

// ---------------- transpose: out[k*N+n] = in[n*K+k] ----------------
__global__ void k_transpose(const float* __restrict__ in, float* __restrict__ out,
                            int N, int K) {
    int q = blockIdx.x * 256 + threadIdx.x;
    if (q >= N * K) return;
    int n = q / K, k = q % K;
    out[(size_t)k * N + n] = in[q];
}

// ---------------- pack Whh (1024x256 fp32) -> per-slice reg pack (f16x2) -----
// Scan thread (slice s, tid j) owns row = (j>>7)*256 + s*128 + (j&127);
// rp[(s*512 + j)*128 + p] = pack(W[row][2p], W[row][2p+1]).
__global__ void k_pack_whh_mc(const float* __restrict__ W, u32* __restrict__ out) {
    int q = blockIdx.x * 256 + threadIdx.x;     // 1024*128 = 131072 total
    if (q >= 1024 * 128) return;
    int p = q & 127;
    int j = (q >> 7) & 511;
    int s = q >> 16;                            // 512*128 = 65536 per slice
    int row = ((j >> 7) * 256) + s * 128 + (j & 127);
    out[q] = pack2(W[row * 256 + 2 * p], W[row * 256 + 2 * p + 1]);
}

// ---------------- generic GEMM: C[M,N] = A[M,K] @ Wt[K,N] (+bias/relu/cosine)
__global__ __launch_bounds__(256) void k_gemm(
    const float* __restrict__ A, const float* __restrict__ Wt,
    const float* __restrict__ bias, const float* __restrict__ norms,
    float* __restrict__ C, int M, int N, int K, int mode) {
    __shared__ float As[16 * 512];
    const int tid = threadIdx.x;
    const int m0 = blockIdx.x * 16;
    const int n  = blockIdx.y * 256 + tid;

    for (int i = tid; i < 16 * K; i += 256) As[i] = A[(size_t)m0 * K + i];
    __syncthreads();

    float acc[16];
#pragma unroll
    for (int m = 0; m < 16; ++m) acc[m] = 0.f;

#pragma unroll 4
    for (int k = 0; k < K; ++k) {
        float w = Wt[(size_t)k * N + n];
#pragma unroll
        for (int m = 0; m < 16; ++m) acc[m] += As[m * K + k] * w;
    }

    float bn = bias ? bias[n] : 0.f;
#pragma unroll
    for (int m = 0; m < 16; ++m) {
        float v = acc[m] + bn;
        if (mode == 1) v = fmaxf(v, 0.f);
        if (mode == 2) {
            float d = norms[m0 + m] * norms[n];
            v = 1.f - fmaxf(acc[m] / d, 1e-6f);
        }
        C[(size_t)(m0 + m) * N + n] = v;
    }
}

// ---------------- row norms of e (4096 x 256) ----------------
__global__ void k_norms(const float* __restrict__ e, float* __restrict__ norms) {
    int i = blockIdx.x, lane = threadIdx.x;
    float s = 0.f;
    for (int k = lane; k < 256; k += 64) { float v = e[i * 256 + k]; s += v * v; }
    for (int off = 32; off; off >>= 1) s += __shfl_down(s, off);
    if (lane == 0) norms[i] = sqrtf(s);
}

// ---------------- 2-CU-per-direction recurrent scan ----------------
// r6 skeleton (proven): 16 blocks, workers bid in {0,1,8,9}: dir=bid&7, s=bid>>3.
// Slice s owns units [128s,128s+128): thread (g=tid>>7, u=tid&127) owns row
// g*256 + s*128 + u with its 128 f16x2 weights in VGPRs.
//
// NEW vs r6: h is no longer broadcast-read from LDS (256 ds_read_b128/CU/step
// was the measured structural bottleneck, ~3000 cy/step). Instead lane l loads
// only h[l] and h[64+l] (2 ds_read_b32, 2-way alias = free), and each word is
// broadcast in-register via v_readlane into an SGPR feeding v_dot2_f32_f16
// directly (VOP3P allows one scalar src). Same ascending-k single-accumulator
// chain -> bitwise-identical z.
//
// Cross-CU h exchange: tag+payload in ONE u64 (tag=t+1 | 2xf16 h), relaxed
// agent-scope store (fire-and-forget, no fence, no vmcnt drain). Consumer
// polls acquire until tag==t+1: detect + data in one LLC trip. Slots
// double-buffered by t&1 -> race-free.
__global__ __launch_bounds__(512, 2) void k_scan_mc2(
    const float* __restrict__ xs, const u32* __restrict__ rp,
    u64* __restrict__ ex, float* __restrict__ hout) {
    __shared__ alignas(16) u32 hloc[128];    // full h(t-1), f16x2 packed
    __shared__ float zex[4][128];            // gate-major z exchange

    const int bid = blockIdx.x;
    if ((bid & 7) > 1 || (bid >> 3) > 1) return;
    const int dir = bid & 7;
    const int s   = bid >> 3;
    const int tid = threadIdx.x;
    const int g   = tid >> 7;
    const int u_  = tid & 127;
    const int lane = tid & 63;
    const int row = g * 256 + s * 128 + u_;

    xs += (size_t)dir * (T_LEN * G4);
    rp += (size_t)dir * DIRSZ;
    u64* exd = ex + dir * (2 * 2 * 64);      // [par][slice][64]

    u32 regw[128];
    {
        const uint4* rp4 = (const uint4*)(rp + (size_t)(s * 512 + tid) * 128);
#pragma unroll
        for (int p = 0; p < 32; ++p) {
            uint4 v = rp4[p];
            regw[4 * p + 0] = v.x; regw[4 * p + 1] = v.y;
            regw[4 * p + 2] = v.z; regw[4 * p + 3] = v.w;
        }
    }
    if (tid < 128) hloc[tid] = 0u;
    float cst0 = 0.f, cst1 = 0.f;
    __syncthreads();

    int tt = dir ? (T_LEN - 1) : 0;
    const int stp = dir ? -1 : 1;
    float xa = xs[(size_t)tt * G4 + row];

    for (int t = 0; t < T_LEN; ++t) {
        float a = xa;
        int tn = (t + 1 < T_LEN) ? tt + stp : tt;
        xa = xs[(size_t)tn * G4 + row];      // prefetch next step (never drained)

        // lane-sliced h fetch: 2 ds_read_b32 per thread (vs 32 ds_read_b128)
        u32 hAv = hloc[lane];
        u32 hBv = hloc[64 + lane];

        // z[row] = xs[row] + Whh[row,:] . h  (ascending k pairs, one acc chain;
        // h word j broadcast via readlane -> SGPR operand of v_dot2_f32_f16)
#pragma unroll
        for (int j = 0; j < 64; ++j)
            a = dot2s(regw[j], (u32)__builtin_amdgcn_readlane((int)hAv, j), a);
#pragma unroll
        for (int j = 0; j < 64; ++j)
            a = dot2s(regw[64 + j], (u32)__builtin_amdgcn_readlane((int)hBv, j), a);

        zex[g][u_] = a;
        step_barrier();

        if (tid < 64) {                       // wave 0: gates for units 2t,2t+1
            float zi0 = zex[0][2 * tid], zi1 = zex[0][2 * tid + 1];
            float zf0 = zex[1][2 * tid], zf1 = zex[1][2 * tid + 1];
            float zg0 = zex[2][2 * tid], zg1 = zex[2][2 * tid + 1];
            float zo0 = zex[3][2 * tid], zo1 = zex[3][2 * tid + 1];

            float si0 = 1.f / (1.f + __expf(-zi0));
            float sf0 = 1.f / (1.f + __expf(-zf0));
            float so0 = 1.f / (1.f + __expf(-zo0));
            float tg0 = 1.f - 2.f / (__expf(2.f * zg0) + 1.f);
            cst0 = sf0 * cst0 + si0 * tg0;
            float th0 = 1.f - 2.f / (__expf(2.f * cst0) + 1.f);
            float hv0 = so0 * th0;

            float si1 = 1.f / (1.f + __expf(-zi1));
            float sf1 = 1.f / (1.f + __expf(-zf1));
            float so1 = 1.f / (1.f + __expf(-zo1));
            float tg1 = 1.f - 2.f / (__expf(2.f * zg1) + 1.f);
            cst1 = sf1 * cst1 + si1 * tg1;
            float th1 = 1.f - 2.f / (__expf(2.f * cst1) + 1.f);
            float hv1 = so1 * th1;

            u32 hp = pack2(hv0, hv1);
            ((u32*)hloc)[s * 64 + tid] = hp;                // own chunk locally
            u64 pay = ((u64)(u32)(t + 1) << 32) | (u64)hp;  // tag | payload
            __hip_atomic_store(&exd[((t & 1) * 2 + s) * 64 + tid], pay,
                               __ATOMIC_RELAXED, __HIP_MEMORY_SCOPE_AGENT);
            float2 hvv; hvv.x = hv0; hvv.y = hv1;
            *(float2*)&hout[(size_t)tt * 512 + dir * 256 + s * 128 + 2 * tid] = hvv;
        } else if (tid < 128) {               // wave 1: poll remote slice
            if (t + 1 < T_LEN) {
                int j  = tid - 64;
                int rs = 1 - s;
                u64 v;
                do {
                    v = __hip_atomic_load(&exd[((t & 1) * 2 + rs) * 64 + j],
                                          __ATOMIC_ACQUIRE,
                                          __HIP_MEMORY_SCOPE_AGENT);
                } while ((u32)(v >> 32) != (u32)(t + 1));
                ((u32*)hloc)[rs * 64 + j] = (u32)v;
            }
        }
        step_barrier();
        tt = tn;
    }
}

// ---------------- launcher ----------------
extern "C" void kernel_launch(void* const* d_in, const int* in_sizes, int n_in,
                              void* d_out, int out_size, void* d_ws, size_t ws_size,
                              hipStream_t stream) {
    const float* x       = (const float*)d_in[0];
    const float* wih_l0f = (const float*)d_in[1];
    const float* whh_l0f = (const float*)d_in[2];
    const float* b_l0f   = (const float*)d_in[3];
    const float* wih_l0b = (const float*)d_in[4];
    const float* whh_l0b = (const float*)d_in[5];
    const float* b_l0b   = (const float*)d_in[6];
    const float* wih_l1f = (const float*)d_in[7];
    const float* whh_l1f = (const float*)d_in[8];
    const float* b_l1f   = (const float*)d_in[9];
    const float* wih_l1b = (const float*)d_in[10];
    const float* whh_l1b = (const float*)d_in[11];
    const float* b_l1b   = (const float*)d_in[12];
    const float* fc1_w   = (const float*)d_in[13];
    const float* fc1_b   = (const float*)d_in[14];
    const float* fc2_w   = (const float*)d_in[15];
    const float* fc2_b   = (const float*)d_in[16];
    float* outp = (float*)d_out;

    char* ws = (char*)d_ws;
    size_t off = 0;
    auto alloc = [&](size_t nbytes) {
        char* p = ws + off;
        off += (nbytes + 255) & ~(size_t)255;
        return p;
    };
    float* xs0   = (float*)alloc((size_t)2 * T_LEN * G4 * 4);
    float* xs1   = (float*)alloc((size_t)2 * T_LEN * G4 * 4);
    float* h1    = (float*)alloc((size_t)T_LEN * 512 * 4);
    float* h2    = (float*)alloc((size_t)T_LEN * 512 * 4);
    float* zb    = (float*)alloc((size_t)T_LEN * 256 * 4);
    float* eb    = (float*)alloc((size_t)T_LEN * 256 * 4);
    float* etb   = (float*)alloc((size_t)T_LEN * 256 * 4);
    float* nrm   = (float*)alloc((size_t)T_LEN * 4);
    float* wt0f  = (float*)alloc((size_t)128 * 1024 * 4);
    float* wt0b  = (float*)alloc((size_t)128 * 1024 * 4);
    float* wt1f  = (float*)alloc((size_t)512 * 1024 * 4);
    float* wt1b  = (float*)alloc((size_t)512 * 1024 * 4);
    float* wtf1  = (float*)alloc((size_t)512 * 256 * 4);
    float* wtf2  = (float*)alloc((size_t)256 * 256 * 4);
    u32*   rpm0  = (u32*)alloc((size_t)2 * DIRSZ * 4);
    u32*   rpm1  = (u32*)alloc((size_t)2 * DIRSZ * 4);
    u64*   exA   = (u64*)alloc((size_t)512 * 8);   // 2 dir x 2 par x 2 sl x 64
    u64*   exB   = (u64*)alloc((size_t)512 * 8);

    // reset exchange tags (every launch / graph replay); exA,exB contiguous
    k_zero<<<8, 256, 0, stream>>>((u32*)exA, 2048);

    // weight transposes
    k_transpose<<<(1024 * 128 + 255) / 256, 256, 0, stream>>>(wih_l0f, wt0f, 1024, 128);
    k_transpose<<<(1024 * 128 + 255) / 256, 256, 0, stream>>>(wih_l0b, wt0b, 1024, 128);
    k_transpose<<<(1024 * 512 + 255) / 256, 256, 0, stream>>>(wih_l1f, wt1f, 1024, 512);
    k_transpose<<<(1024 * 512 + 255) / 256, 256, 0, stream>>>(wih_l1b, wt1b, 1024, 512);
    k_transpose<<<(256 * 512 + 255) / 256, 256, 0, stream>>>(fc1_w, wtf1, 256, 512);
    k_transpose<<<(256 * 256 + 255) / 256, 256, 0, stream>>>(fc2_w, wtf2, 256, 256);

    // recurrent weight packs (per-slice row->thread mapping)
    k_pack_whh_mc<<<512, 256, 0, stream>>>(whh_l0f, rpm0);
    k_pack_whh_mc<<<512, 256, 0, stream>>>(whh_l0b, rpm0 + DIRSZ);
    k_pack_whh_mc<<<512, 256, 0, stream>>>(whh_l1f, rpm1);
    k_pack_whh_mc<<<512, 256, 0, stream>>>(whh_l1b, rpm1 + DIRSZ);

    dim3 g1024(T_LEN / 16, 4);
    // layer 0 input projections
    k_gemm<<<g1024, 256, 0, stream>>>(x, wt0f, b_l0f, nullptr, xs0, T_LEN, 1024, 128, 0);
    k_gemm<<<g1024, 256, 0, stream>>>(x, wt0b, b_l0b, nullptr, xs0 + (size_t)T_LEN * G4, T_LEN, 1024, 128, 0);
    // layer 0 scan (2 dirs x 2 slices on 4 CUs)
    k_scan_mc2<<<16, 512, 0, stream>>>(xs0, rpm0, exA, h1);
    // layer 1 input projections
    k_gemm<<<g1024, 256, 0, stream>>>(h1, wt1f, b_l1f, nullptr, xs1, T_LEN, 1024, 512, 0);
    k_gemm<<<g1024, 256, 0, stream>>>(h1, wt1b, b_l1b, nullptr, xs1 + (size_t)T_LEN * G4, T_LEN, 1024, 512, 0);
    // layer 1 scan
    k_scan_mc2<<<16, 512, 0, stream>>>(xs1, rpm1, exB, h2);
    // FC head
    k_gemm<<<dim3(T_LEN / 16, 1), 256, 0, stream>>>(h2, wtf1, fc1_b, nullptr, zb, T_LEN, 256, 512, 1);
    k_gemm<<<dim3(T_LEN / 16, 1), 256, 0, stream>>>(zb, wtf2, fc2_b, nullptr, eb, T_LEN, 256, 256, 0);
    // cosine-similarity output
    k_transpose<<<(T_LEN * 256 + 255) / 256, 256, 0, stream>>>(eb, etb, T_LEN, 256);
    k_norms<<<T_LEN, 64, 0, stream>>>(eb, nrm);
    k_gemm<<<dim3(T_LEN / 16, T_LEN / 256), 256, 0, stream>>>(eb, etb, nullptr, nrm, outp, T_LEN, T_LEN, 256, 2);
}

// Round 8
// 14911.383 us; speedup vs baseline: 1.1028x; 1.1028x over previous
//
#include <hip/hip_runtime.h>
#include <hip/hip_fp16.h>

#define T_LEN 4096
#define HID   256
#define G4    1024
#define DIRSZ (1024 * 128)   // packed weight u32 per direction (1024 rows x 128 pairs)

typedef unsigned int u32;
typedef unsigned long long u64;
typedef _Float16 half2_t __attribute__((ext_vector_type(2)));

__device__ __forceinline__ float dot2f(u32 w, u32 h, float acc) {
#if __has_builtin(__builtin_amdgcn_fdot2)
    return __builtin_amdgcn_fdot2(__builtin_bit_cast(half2_t, w),
                                  __builtin_bit_cast(half2_t, h), acc, false);
#else
    __half2 wh = __builtin_bit_cast(__half2, w);
    __half2 hh = __builtin_bit_cast(__half2, h);
    float2 wf = __half22float2(wh), hf = __half22float2(hh);
    return acc + wf.x * hf.x + wf.y * hf.y;
#endif
}

// dot with wave-uniform h held in an SGPR (VOP3P permits one scalar source).
__device__ __forceinline__ float dot2s(u32 w, u32 hs, float acc) {
    asm("v_dot2_f32_f16 %0, %1, %2, %0" : "+v"(acc) : "v"(w), "s"(hs));
    return acc;
}

__device__ __forceinline__ u32 pack2(float a, float b) {
    unsigned short lo = __half_as_ushort(__float2half(a));
    unsigned short hi = __half_as_ushort(__float2half(b));
    return ((u32)hi << 16) | (u32)lo;
}

// lgkm-only barrier: never drains vmcnt (global stores/loads keep flying)
__device__ __forceinline__ void step_barrier() {
    asm volatile("s_waitcnt lgkmcnt(0)" ::: "memory");
    __builtin_amdgcn_s_barrier();
    __builtin_amdgcn_sched_barrier(0);
}

// ---------------- zero helper (exchange tags must be 0 at each launch) -------
__global__ void k_zero(u32* __restrict__ p, int n) {
    int q = blockIdx.x * 256 + threadIdx.x;
    if (q < n) p[q] = 0u;
}

// ---------------- transpose: out[k*N+n] = in[n*K+k] ----------------
__global__ void k_transpose(const float* __restrict__ in, float* __restrict__ out,
                            int N, int K) {
    int q = blockIdx.x * 256 + threadIdx.x;
    if (q >= N * K) return;
    int n = q / K, k = q % K;
    out[(size_t)k * N + n] = in[q];
}

// ---------------- pack Whh (1024x256 fp32) -> per-slice reg pack (f16x2) -----
// Thread (slice s, tid j) owns row = (j>>7)*256 + s*128 + (j&127).
// OWN-HALF-FIRST k order: p<64 -> h-word 64s+p (own slice units),
//                         p>=64 -> h-word 64(1-s)+(p-64) (remote units).
__global__ void k_pack_whh_mc(const float* __restrict__ W, u32* __restrict__ out) {
    int q = blockIdx.x * 256 + threadIdx.x;     // 1024*128 = 131072 total
    if (q >= 1024 * 128) return;
    int p = q & 127;
    int j = (q >> 7) & 511;
    int s = q >> 16;                            // 512*128 = 65536 per slice
    int row = ((j >> 7) * 256) + s * 128 + (j & 127);
    int w = (p < 64) ? (64 * s + p) : (64 * (1 - s) + (p - 64));
    out[q] = pack2(W[row * 256 + 2 * w], W[row * 256 + 2 * w + 1]);
}

// ---------------- generic GEMM: C[M,N] = A[M,K] @ Wt[K,N] (+bias/relu/cosine)
__global__ __launch_bounds__(256) void k_gemm(
    const float* __restrict__ A, const float* __restrict__ Wt,
    const float* __restrict__ bias, const float* __restrict__ norms,
    float* __restrict__ C, int M, int N, int K, int mode) {
    __shared__ float As[16 * 512];
    const int tid = threadIdx.x;
    const int m0 = blockIdx.x * 16;
    const int n  = blockIdx.y * 256 + tid;

    for (int i = tid; i < 16 * K; i += 256) As[i] = A[(size_t)m0 * K + i];
    __syncthreads();

    float acc[16];
#pragma unroll
    for (int m = 0; m < 16; ++m) acc[m] = 0.f;

#pragma unroll 4
    for (int k = 0; k < K; ++k) {
        float w = Wt[(size_t)k * N + n];
#pragma unroll
        for (int m = 0; m < 16; ++m) acc[m] += As[m * K + k] * w;
    }

    float bn = bias ? bias[n] : 0.f;
#pragma unroll
    for (int m = 0; m < 16; ++m) {
        float v = acc[m] + bn;
        if (mode == 1) v = fmaxf(v, 0.f);
        if (mode == 2) {
            float d = norms[m0 + m] * norms[n];
            v = 1.f - fmaxf(acc[m] / d, 1e-6f);
        }
        C[(size_t)(m0 + m) * N + n] = v;
    }
}

// ---------------- row norms of e (4096 x 256) ----------------
__global__ void k_norms(const float* __restrict__ e, float* __restrict__ norms) {
    int i = blockIdx.x, lane = threadIdx.x;
    float s = 0.f;
    for (int k = lane; k < 256; k += 64) { float v = e[i * 256 + k]; s += v * v; }
    for (int off = 32; off; off >>= 1) s += __shfl_down(s, off);
    if (lane == 0) norms[i] = sqrtf(s);
}

// ---------------- 2-CU-per-direction recurrent scan (v8) ----------------
// r6 frame: 16 blocks, workers bid in {0,1,8,9}: dir=bid&7, s=bid>>3; 512 thr;
// thread owns row g*256+s*128+u (g=tid>>7, u=tid&127), 128 weight u32 in VGPRs
// packed own-half-first.
//
// Per-step schedule (3 lgkm-only barriers):
//  1. own-half dots: hA = hloc[64s+lane] (1 ds_read_b32), then 8-BATCHED
//     readlane->SGPR + v_dot2(SGPR) (batching amortizes the SGPR-write hazard
//     that made r7 issue-bound).  Wave0 then polls the 64 remote u64 slots
//     (tag==t, parity (t-1)&1) and writes hloc[remote] - the remote h has been
//     in flight since the partner's previous gate phase.
//  2. [mid-bar] remote-half dots same way from hloc[64(1-s)+lane].
//  3. [zex-bar] wave0: gates, write hloc own, publish (tag t+1 | h-pair u64,
//     relaxed agent store, fire-and-forget), hout store.  [end-bar]
// Critical path/step ~ RTT + remote-dots + gates (LDS broadcast wall removed).
__global__ __launch_bounds__(512, 2) void k_scan_mc2(
    const float* __restrict__ xs, const u32* __restrict__ rp,
    u64* __restrict__ ex, float* __restrict__ hout) {
    __shared__ alignas(16) u32 hloc[128];    // full h(t-1), f16x2 packed
    __shared__ float zex[4][128];            // gate-major z exchange

    const int bid = blockIdx.x;
    if ((bid & 7) > 1 || (bid >> 3) > 1) return;
    const int dir = bid & 7;
    const int s   = bid >> 3;
    const int rs  = 1 - s;
    const int tid = threadIdx.x;
    const int g   = tid >> 7;
    const int u_  = tid & 127;
    const int lane = tid & 63;
    const int row = g * 256 + s * 128 + u_;

    xs += (size_t)dir * (T_LEN * G4);
    rp += (size_t)dir * DIRSZ;
    u64* exd = ex + dir * (2 * 2 * 64);      // [par][slice][64]

    u32 regw[128];
    {
        const uint4* rp4 = (const uint4*)(rp + (size_t)(s * 512 + tid) * 128);
#pragma unroll
        for (int p = 0; p < 32; ++p) {
            uint4 v = rp4[p];
            regw[4 * p + 0] = v.x; regw[4 * p + 1] = v.y;
            regw[4 * p + 2] = v.z; regw[4 * p + 3] = v.w;
        }
    }
    if (tid < 128) hloc[tid] = 0u;
    float cst0 = 0.f, cst1 = 0.f;
    __syncthreads();

    int tt = dir ? (T_LEN - 1) : 0;
    const int stp = dir ? -1 : 1;
    float xa = xs[(size_t)tt * G4 + row];

    for (int t = 0; t < T_LEN; ++t) {
        float a = xa;
        int tn = (t + 1 < T_LEN) ? tt + stp : tt;
        xa = xs[(size_t)tn * G4 + row];      // prefetch next step (never drained)

        // ---- phase 1: own-half dots (h produced locally last step) ----
        u32 hA = hloc[64 * s + lane];
#pragma unroll
        for (int jb = 0; jb < 64; jb += 8) {
            u32 sb[8];
#pragma unroll
            for (int qq = 0; qq < 8; ++qq)
                sb[qq] = (u32)__builtin_amdgcn_readlane((int)hA, jb + qq);
#pragma unroll
            for (int qq = 0; qq < 8; ++qq)
                a = dot2s(regw[jb + qq], sb[qq], a);
        }

        // wave0: poll remote h(t-1) (in flight during phase 1) into hloc
        if (tid < 64 && t > 0) {
            u64 v;
            do {
                v = __hip_atomic_load(&exd[(((t & 1) ^ 1) * 2 + rs) * 64 + lane],
                                      __ATOMIC_ACQUIRE, __HIP_MEMORY_SCOPE_AGENT);
            } while ((u32)(v >> 32) != (u32)t);
            hloc[64 * rs + lane] = (u32)v;
        }
        step_barrier();

        // ---- phase 2: remote-half dots ----
        u32 hB = hloc[64 * rs + lane];
#pragma unroll
        for (int jb = 0; jb < 64; jb += 8) {
            u32 sb[8];
#pragma unroll
            for (int qq = 0; qq < 8; ++qq)
                sb[qq] = (u32)__builtin_amdgcn_readlane((int)hB, jb + qq);
#pragma unroll
            for (int qq = 0; qq < 8; ++qq)
                a = dot2s(regw[64 + jb + qq], sb[qq], a);
        }

        zex[g][u_] = a;
        step_barrier();

        // ---- phase 3: gates on wave0 (units s*128 + 2*tid, +1) ----
        if (tid < 64) {
            float zi0 = zex[0][2 * tid], zi1 = zex[0][2 * tid + 1];
            float zf0 = zex[1][2 * tid], zf1 = zex[1][2 * tid + 1];
            float zg0 = zex[2][2 * tid], zg1 = zex[2][2 * tid + 1];
            float zo0 = zex[3][2 * tid], zo1 = zex[3][2 * tid + 1];

            float si0 = 1.f / (1.f + __expf(-zi0));
            float sf0 = 1.f / (1.f + __expf(-zf0));
            float so0 = 1.f / (1.f + __expf(-zo0));
            float tg0 = 1.f - 2.f / (__expf(2.f * zg0) + 1.f);
            cst0 = sf0 * cst0 + si0 * tg0;
            float th0 = 1.f - 2.f / (__expf(2.f * cst0) + 1.f);
            float hv0 = so0 * th0;

            float si1 = 1.f / (1.f + __expf(-zi1));
            float sf1 = 1.f / (1.f + __expf(-zf1));
            float so1 = 1.f / (1.f + __expf(-zo1));
            float tg1 = 1.f - 2.f / (__expf(2.f * zg1) + 1.f);
            cst1 = sf1 * cst1 + si1 * tg1;
            float th1 = 1.f - 2.f / (__expf(2.f * cst1) + 1.f);
            float hv1 = so1 * th1;

            u32 hp = pack2(hv0, hv1);
            hloc[64 * s + tid] = hp;                        // own chunk locally
            u64 pay = ((u64)(u32)(t + 1) << 32) | (u64)hp;  // tag | payload
            __hip_atomic_store(&exd[((t & 1) * 2 + s) * 64 + tid], pay,
                               __ATOMIC_RELAXED, __HIP_MEMORY_SCOPE_AGENT);
            float2 hvv; hvv.x = hv0; hvv.y = hv1;
            *(float2*)&hout[(size_t)tt * 512 + dir * 256 + s * 128 + 2 * tid] = hvv;
        }
        step_barrier();
        tt = tn;
    }
}

// ---------------- launcher ----------------
extern "C" void kernel_launch(void* const* d_in, const int* in_sizes, int n_in,
                              void* d_out, int out_size, void* d_ws, size_t ws_size,
                              hipStream_t stream) {
    const float* x       = (const float*)d_in[0];
    const float* wih_l0f = (const float*)d_in[1];
    const float* whh_l0f = (const float*)d_in[2];
    const float* b_l0f   = (const float*)d_in[3];
    const float* wih_l0b = (const float*)d_in[4];
    const float* whh_l0b = (const float*)d_in[5];
    const float* b_l0b   = (const float*)d_in[6];
    const float* wih_l1f = (const float*)d_in[7];
    const float* whh_l1f = (const float*)d_in[8];
    const float* b_l1f   = (const float*)d_in[9];
    const float* wih_l1b = (const float*)d_in[10];
    const float* whh_l1b = (const float*)d_in[11];
    const float* b_l1b   = (const float*)d_in[12];
    const float* fc1_w   = (const float*)d_in[13];
    const float* fc1_b   = (const float*)d_in[14];
    const float* fc2_w   = (const float*)d_in[15];
    const float* fc2_b   = (const float*)d_in[16];
    float* outp = (float*)d_out;

    char* ws = (char*)d_ws;
    size_t off = 0;
    auto alloc = [&](size_t nbytes) {
        char* p = ws + off;
        off += (nbytes + 255) & ~(size_t)255;
        return p;
    };
    float* xs0   = (float*)alloc((size_t)2 * T_LEN * G4 * 4);
    float* xs1   = (float*)alloc((size_t)2 * T_LEN * G4 * 4);
    float* h1    = (float*)alloc((size_t)T_LEN * 512 * 4);
    float* h2    = (float*)alloc((size_t)T_LEN * 512 * 4);
    float* zb    = (float*)alloc((size_t)T_LEN * 256 * 4);
    float* eb    = (float*)alloc((size_t)T_LEN * 256 * 4);
    float* etb   = (float*)alloc((size_t)T_LEN * 256 * 4);
    float* nrm   = (float*)alloc((size_t)T_LEN * 4);
    float* wt0f  = (float*)alloc((size_t)128 * 1024 * 4);
    float* wt0b  = (float*)alloc((size_t)128 * 1024 * 4);
    float* wt1f  = (float*)alloc((size_t)512 * 1024 * 4);
    float* wt1b  = (float*)alloc((size_t)512 * 1024 * 4);
    float* wtf1  = (float*)alloc((size_t)512 * 256 * 4);
    float* wtf2  = (float*)alloc((size_t)256 * 256 * 4);
    u32*   rpm0  = (u32*)alloc((size_t)2 * DIRSZ * 4);
    u32*   rpm1  = (u32*)alloc((size_t)2 * DIRSZ * 4);
    u64*   exA   = (u64*)alloc((size_t)512 * 8);   // 2 dir x 2 par x 2 sl x 64
    u64*   exB   = (u64*)alloc((size_t)512 * 8);

    // reset exchange tags (every launch / graph replay); exA,exB contiguous
    k_zero<<<8, 256, 0, stream>>>((u32*)exA, 2048);

    // weight transposes
    k_transpose<<<(1024 * 128 + 255) / 256, 256, 0, stream>>>(wih_l0f, wt0f, 1024, 128);
    k_transpose<<<(1024 * 128 + 255) / 256, 256, 0, stream>>>(wih_l0b, wt0b, 1024, 128);
    k_transpose<<<(1024 * 512 + 255) / 256, 256, 0, stream>>>(wih_l1f, wt1f, 1024, 512);
    k_transpose<<<(1024 * 512 + 255) / 256, 256, 0, stream>>>(wih_l1b, wt1b, 1024, 512);
    k_transpose<<<(256 * 512 + 255) / 256, 256, 0, stream>>>(fc1_w, wtf1, 256, 512);
    k_transpose<<<(256 * 256 + 255) / 256, 256, 0, stream>>>(fc2_w, wtf2, 256, 256);

    // recurrent weight packs (own-half-first k order)
    k_pack_whh_mc<<<512, 256, 0, stream>>>(whh_l0f, rpm0);
    k_pack_whh_mc<<<512, 256, 0, stream>>>(whh_l0b, rpm0 + DIRSZ);
    k_pack_whh_mc<<<512, 256, 0, stream>>>(whh_l1f, rpm1);
    k_pack_whh_mc<<<512, 256, 0, stream>>>(whh_l1b, rpm1 + DIRSZ);

    dim3 g1024(T_LEN / 16, 4);
    // layer 0 input projections
    k_gemm<<<g1024, 256, 0, stream>>>(x, wt0f, b_l0f, nullptr, xs0, T_LEN, 1024, 128, 0);
    k_gemm<<<g1024, 256, 0, stream>>>(x, wt0b, b_l0b, nullptr, xs0 + (size_t)T_LEN * G4, T_LEN, 1024, 128, 0);
    // layer 0 scan (2 dirs x 2 slices on 4 CUs)
    k_scan_mc2<<<16, 512, 0, stream>>>(xs0, rpm0, exA, h1);
    // layer 1 input projections
    k_gemm<<<g1024, 256, 0, stream>>>(h1, wt1f, b_l1f, nullptr, xs1, T_LEN, 1024, 512, 0);
    k_gemm<<<g1024, 256, 0, stream>>>(h1, wt1b, b_l1b, nullptr, xs1 + (size_t)T_LEN * G4, T_LEN, 1024, 512, 0);
    // layer 1 scan
    k_scan_mc2<<<16, 512, 0, stream>>>(xs1, rpm1, exB, h2);
    // FC head
    k_gemm<<<dim3(T_LEN / 16, 1), 256, 0, stream>>>(h2, wtf1, fc1_b, nullptr, zb, T_LEN, 256, 512, 1);
    k_gemm<<<dim3(T_LEN / 16, 1), 256, 0, stream>>>(zb, wtf2, fc2_b, nullptr, eb, T_LEN, 256, 256, 0);
    // cosine-similarity output
    k_transpose<<<(T_LEN * 256 + 255) / 256, 256, 0, stream>>>(eb, etb, T_LEN, 256);
    k_norms<<<T_LEN, 64, 0, stream>>>(eb, nrm);
    k_gemm<<<dim3(T_LEN / 16, T_LEN / 256), 256, 0, stream>>>(eb, etb, nullptr, nrm, outp, T_LEN, T_LEN, 256, 2);
}